// Round 1
// baseline (868.102 us; speedup 1.0000x reference)
//
#include <hip/hip_runtime.h>
#include <math.h>

#define NA 30
#define ND 435          // NA*(NA-1)/2
#define NI 90           // 3*NA
#define NP 12
#define NNB (NA-1)

struct Pre {
  int   pidx[NP][ND];      // pair permutation: d -> image pair under perm p
  int   pinv[NP][ND];      // inverse pair permutation
  int   sigma[NP][NA];     // atom permutation
  int   sigma_inv[NP][NA];
  int   rowv[ND];
  int   colv[ND];
  int   nbr[NA][NNB];      // the 29 pairs containing atom a
  float rjp[NP][ND];       // R_desc[j][pidx[p][d]]
  float rdj[ND][3];        // R_d_desc[j]
};

__device__ __forceinline__ int pair_index(int x, int y) {
  int hi = max(x, y), lo = min(x, y);
  return hi * (hi - 1) / 2 + lo;
}

__global__ void pre_kernel(const float* __restrict__ R_desc,
                           const float* __restrict__ R_d_desc,
                           const int* __restrict__ tpl,
                           const int* __restrict__ jptr,
                           Pre* ws) {
  const int tid = threadIdx.x;
  const int nthr = blockDim.x;
  const int j = *jptr;

  for (int d = tid; d < ND; d += nthr) {
    int a = (int)floorf((1.0f + sqrtf(1.0f + 8.0f * (float)d)) * 0.5f);
    while (a * (a - 1) / 2 > d) --a;
    while ((a + 1) * a / 2 <= d) ++a;
    ws->rowv[d] = a;
    ws->colv[d] = d - a * (a - 1) / 2;
  }
  for (int idx = tid; idx < NP * ND; idx += nthr) {
    int d = idx / NP, p = idx % NP;          // tpl layout: [d*NP + p]
    int t = tpl[idx] - p * ND;
    ws->pidx[p][d] = t;
    ws->rjp[p][d] = R_desc[(size_t)j * ND + t];
  }
  for (int idx = tid; idx < ND * 3; idx += nthr) {
    ((float*)ws->rdj)[idx] = R_d_desc[(size_t)j * (ND * 3) + idx];
  }
  for (int a = tid; a < NA; a += nthr) {
    int k = 0;
    for (int u = 0; u < NA; ++u)
      if (u != a) ws->nbr[a][k++] = pair_index(a, u);
  }
  __syncthreads();
  for (int idx = tid; idx < NP * ND; idx += nthr) {
    int d = idx / NP, p = idx % NP;
    ws->pinv[p][ws->pidx[p][d]] = d;
  }
  // recover atom permutation sigma_p: images of two pairs containing a share
  // exactly one atom = sigma_p(a)
  for (int idx = tid; idx < NP * NA; idx += nthr) {
    int p = idx / NA, a = idx % NA;
    int u1 = (a == 0) ? 1 : 0;
    int u2 = (a <= 1) ? 2 : 1;
    int e1 = ws->pidx[p][pair_index(a, u1)];
    int e2 = ws->pidx[p][pair_index(a, u2)];
    int r1 = ws->rowv[e1], c1 = ws->colv[e1];
    int r2 = ws->rowv[e2], c2 = ws->colv[e2];
    int sa = (r1 == r2 || r1 == c2) ? r1 : c1;
    ws->sigma[p][a] = sa;
  }
  __syncthreads();
  for (int idx = tid; idx < NP * NA; idx += nthr) {
    int p = idx / NA, a = idx % NA;
    ws->sigma_inv[p][ws->sigma[p][a]] = a;
  }
}

__global__ __launch_bounds__(256) void gdml_kernel(
    const float* __restrict__ R_desc,
    const float* __restrict__ R_d_desc,
    const Pre* __restrict__ ws,
    float* __restrict__ out) {
  const int n = blockIdx.x;
  const int tid = threadIdx.x;

  __shared__ float xd[NP][ND];       // 20.9 KB  q*(R_desc[n]-rjp)
  __shared__ float Rdn_l[ND][3];     // 5.2 KB
  __shared__ float Rdj_l[ND][3];     // 5.2 KB
  __shared__ float inner_s[NP][NI];  // 4.3 KB
  __shared__ float v_s[NP][NI];      // 4.3 KB
  __shared__ float Hh[NA][NP][9];    // 13.0 KB  heavy 3x3 blocks (sigma-matched)
  __shared__ float dist2[NP];
  __shared__ float e_s[NP], e1_s[NP];

  const float q   = 0.22360679774997896f;   // sqrt(5)/10
  const float qq3 = 0.016666666666666666f;  // q*q/3

  for (int idx = tid; idx < ND * 3; idx += 256) {
    Rdn_l[idx / 3][idx % 3] = R_d_desc[(size_t)n * (ND * 3) + idx];
    Rdj_l[idx / 3][idx % 3] = ((const float*)ws->rdj)[idx];
  }
  if (tid < NP) dist2[tid] = 0.f;
  __syncthreads();

  // x-diffs and squared distances
  float acc[NP];
#pragma unroll
  for (int p = 0; p < NP; ++p) acc[p] = 0.f;
  for (int d = tid; d < ND; d += 256) {
    float rn = R_desc[(size_t)n * ND + d];
#pragma unroll
    for (int p = 0; p < NP; ++p) {
      float x = q * (rn - ws->rjp[p][d]);
      xd[p][d] = x;
      acc[p] += x * x;
    }
  }
#pragma unroll
  for (int p = 0; p < NP; ++p) {
    float a = acc[p];
    for (int off = 32; off; off >>= 1) a += __shfl_xor(a, off);
    if ((tid & 63) == 0) atomicAdd(&dist2[p], a);
  }
  __syncthreads();
  if (tid < NP) {
    float dist = sqrtf(dist2[tid]);
    float e = expf(-dist) * qq3;
    e_s[tid] = e;
    e1_s[tid] = e * (1.f + dist);
  }

  // inner[p][3a+c] and v[p][3a+c] via 29-pair gathers (no atomics)
  for (int it = tid; it < NP * NI; it += 256) {
    int p = it / NI, ii = it % NI;
    int a = ii / 3, c = ii % 3;
    float si = 0.f, sv = 0.f;
    for (int k = 0; k < NNB; ++k) {
      int d = ws->nbr[a][k];
      float s = (ws->rowv[d] == a) ? 1.f : -1.f;
      sv += s * xd[p][d] * Rdn_l[d][c];
      int di = ws->pinv[p][d];
      si += s * xd[p][di] * Rdj_l[d][c];
    }
    inner_s[p][ii] = si;
    v_s[p][ii] = sv;
  }

  // heavy H blocks: (a, p) -> a2 = sigma_p(a), dense 29-sum per (c,c')
  for (int it = tid; it < NA * NP * 9; it += 256) {
    int cpair = it % 9;
    int ap = it / 9;
    int p = ap % NP, a = ap / NP;
    int c = cpair / 3, c2 = cpair % 3;
    int a2 = ws->sigma[p][a];
    float h = 0.f;
    for (int k = 0; k < NNB; ++k) {
      int d = ws->nbr[a][k];
      float s = (ws->rowv[d] == a) ? 1.f : -1.f;
      int d2 = ws->pidx[p][d];
      float s2 = (ws->rowv[d2] == a2) ? 1.f : -1.f;
      h += (s * s2) * Rdn_l[d][c] * Rdj_l[d2][c2];
    }
    Hh[a][p][cpair] = h;
  }
  __syncthreads();

  // final assembly: out[n, kk, i] = sum_p e*v*inner - e1*H
  float* outn = out + (size_t)n * (NI * NI);
  for (int it = tid; it < NI * NI; it += 256) {
    int kk = it / NI, i = it % NI;
    int a = kk / 3, c = kk % 3;
    int a2 = i / 3, c2 = i % 3;
    float accv = 0.f;
    for (int p = 0; p < NP; ++p) {
      accv += e_s[p] * v_s[p][kk] * inner_s[p][i];
      float h;
      if (ws->sigma[p][a] == a2) {
        h = Hh[a][p][c * 3 + c2];
      } else {
        int u = ws->sigma_inv[p][a2];       // u != a since sigma_p(a) != a2
        int d = pair_index(a, u);
        float s = (a > u) ? 1.f : -1.f;
        int d2 = ws->pidx[p][d];
        float s2 = (ws->rowv[d2] == a2) ? 1.f : -1.f;
        h = (s * s2) * Rdn_l[d][c] * Rdj_l[d2][c2];
      }
      accv -= e1_s[p] * h;
    }
    outn[it] = accv;
  }
}

extern "C" void kernel_launch(void* const* d_in, const int* in_sizes, int n_in,
                              void* d_out, int out_size, void* d_ws, size_t ws_size,
                              hipStream_t stream) {
  const float* R_desc   = (const float*)d_in[0];
  const float* R_d_desc = (const float*)d_in[1];
  const int*   tpl      = (const int*)d_in[2];
  const int*   jptr     = (const int*)d_in[3];
  float* out = (float*)d_out;
  Pre* ws = (Pre*)d_ws;

  const int n_train = in_sizes[0] / ND;

  hipLaunchKernelGGL(pre_kernel, dim3(1), dim3(256), 0, stream,
                     R_desc, R_d_desc, tpl, jptr, ws);
  hipLaunchKernelGGL(gdml_kernel, dim3(n_train), dim3(256), 0, stream,
                     R_desc, R_d_desc, ws, out);
}

// Round 2
// 220.105 us; speedup vs baseline: 3.9440x; 3.9440x over previous
//
#include <hip/hip_runtime.h>
#include <math.h>

#define NA 30
#define ND 435          // NA*(NA-1)/2
#define NI 90           // 3*NA
#define NP 12
#define NNB (NA-1)

struct Pre {
  int   pidx[NP][ND];      // pair permutation: d -> image pair under perm p
  int   pinv[NP][ND];      // inverse pair permutation
  int   sigma[NP][NA];     // atom permutation
  int   sigma_inv[NP][NA];
  int   rowv[ND];
  int   colv[ND];
  int   nbr[NA][NNB];      // the 29 pairs containing atom a
  float rjp[NP][ND];       // R_desc[j][pidx[p][d]]
  float rdj[ND][3];        // R_d_desc[j]
  // packed tables (branch-free hot loops):
  // gtab: d | pinv<<9 | pidx<<18 | (s(d,a)>0)<<27 | (s(d,a)*s(d2,sigma_p(a))>0)<<28
  unsigned int gtab[NA][NP][NNB];
  // stab: d1 | d2<<9 | code<<18   code: 0=heavy(skip), 1=+, 2=-
  unsigned int stab[NA][NA][NP];
};

__device__ __forceinline__ int pair_index(int x, int y) {
  int hi = max(x, y), lo = min(x, y);
  return hi * (hi - 1) / 2 + lo;
}

__global__ void pre_kernel(const float* __restrict__ R_desc,
                           const float* __restrict__ R_d_desc,
                           const int* __restrict__ tpl,
                           const int* __restrict__ jptr,
                           Pre* ws) {
  const int tid = threadIdx.x;
  const int nthr = blockDim.x;
  const int j = *jptr;

  for (int d = tid; d < ND; d += nthr) {
    int a = (int)floorf((1.0f + sqrtf(1.0f + 8.0f * (float)d)) * 0.5f);
    while (a * (a - 1) / 2 > d) --a;
    while ((a + 1) * a / 2 <= d) ++a;
    ws->rowv[d] = a;
    ws->colv[d] = d - a * (a - 1) / 2;
  }
  for (int idx = tid; idx < NP * ND; idx += nthr) {
    int d = idx / NP, p = idx % NP;          // tpl layout: [d*NP + p]
    int t = tpl[idx] - p * ND;
    ws->pidx[p][d] = t;
    ws->rjp[p][d] = R_desc[(size_t)j * ND + t];
  }
  for (int idx = tid; idx < ND * 3; idx += nthr) {
    ((float*)ws->rdj)[idx] = R_d_desc[(size_t)j * (ND * 3) + idx];
  }
  for (int a = tid; a < NA; a += nthr) {
    int k = 0;
    for (int u = 0; u < NA; ++u)
      if (u != a) ws->nbr[a][k++] = pair_index(a, u);
  }
  __syncthreads();
  for (int idx = tid; idx < NP * ND; idx += nthr) {
    int d = idx / NP, p = idx % NP;
    ws->pinv[p][ws->pidx[p][d]] = d;
  }
  // recover atom permutation sigma_p
  for (int idx = tid; idx < NP * NA; idx += nthr) {
    int p = idx / NA, a = idx % NA;
    int u1 = (a == 0) ? 1 : 0;
    int u2 = (a <= 1) ? 2 : 1;
    int e1 = ws->pidx[p][pair_index(a, u1)];
    int e2 = ws->pidx[p][pair_index(a, u2)];
    int r1 = ws->rowv[e1], c1 = ws->colv[e1];
    int r2 = ws->rowv[e2], c2 = ws->colv[e2];
    int sa = (r1 == r2 || r1 == c2) ? r1 : c1;
    ws->sigma[p][a] = sa;
  }
  __syncthreads();
  for (int idx = tid; idx < NP * NA; idx += nthr) {
    int p = idx / NA, a = idx % NA;
    ws->sigma_inv[p][ws->sigma[p][a]] = a;
  }
  __syncthreads();
  // gtab
  for (int idx = tid; idx < NA * NP * NNB; idx += nthr) {
    int k = idx % NNB;
    int r = idx / NNB;
    int p = r % NP, a = r / NP;
    int d  = ws->nbr[a][k];
    int di = ws->pinv[p][d];
    int d2 = ws->pidx[p][d];
    int s1 = (ws->rowv[d] == a) ? 1 : 0;
    int a2h = ws->sigma[p][a];
    int s2 = (ws->rowv[d2] == a2h) ? 1 : 0;
    unsigned int u = (unsigned)d | ((unsigned)di << 9) | ((unsigned)d2 << 18);
    if (s1) u |= (1u << 27);
    if (s1 == s2) u |= (1u << 28);
    ws->gtab[a][p][k] = u;
  }
  // stab
  for (int idx = tid; idx < NA * NA * NP; idx += nthr) {
    int p = idx % NP;
    int r = idx / NP;
    int a2 = r % NA, a = r / NA;
    unsigned int u;
    if (ws->sigma[p][a] == a2) {
      u = 0;  // heavy column: handled by heavy pass
    } else {
      int uu = ws->sigma_inv[p][a2];
      int d1 = pair_index(a, uu);
      int d2 = ws->pidx[p][d1];
      int s1 = (ws->rowv[d1] == a) ? 1 : 0;
      int s2 = (ws->rowv[d2] == a2) ? 1 : 0;
      unsigned code = (s1 == s2) ? 1u : 2u;
      u = (unsigned)d1 | ((unsigned)d2 << 9) | (code << 18);
    }
    ws->stab[a][a2][p] = u;
  }
}

__global__ __launch_bounds__(256) void gdml_kernel(
    const float* __restrict__ R_desc,
    const float* __restrict__ R_d_desc,
    const Pre* __restrict__ ws,
    float* __restrict__ out) {
  const int n = blockIdx.x;
  const int tid = threadIdx.x;

  __shared__ float buf[NI * NI];     // 32.4 KB: xd overlay, then T = sum_p e1_p H_p
  __shared__ float Rdn_l[ND][3];     // 5.2 KB
  __shared__ float Rdj_l[ND][3];     // 5.2 KB
  __shared__ float inner_s[NP][NI];  // 4.3 KB
  __shared__ float v_s[NP][NI];      // 4.3 KB  (pre-scaled by e_p)
  __shared__ float dist2[NP];
  __shared__ float e1_s[NP];
  __shared__ float e_s[NP];

  float (*xd)[ND] = (float(*)[ND])buf;   // 12*435 floats fits in buf

  const float q   = 0.22360679774997896f;   // sqrt(5)/10
  const float qq3 = 0.016666666666666666f;  // q*q/3

  // ---- phase 1: load Rdn/Rdj, compute xd + dist ----
  for (int idx = tid; idx < ND * 3; idx += 256) {
    Rdn_l[idx / 3][idx % 3] = R_d_desc[(size_t)n * (ND * 3) + idx];
    Rdj_l[idx / 3][idx % 3] = ((const float*)ws->rdj)[idx];
  }
  if (tid < NP) dist2[tid] = 0.f;

  float acc[NP];
#pragma unroll
  for (int p = 0; p < NP; ++p) acc[p] = 0.f;
  for (int d = tid; d < ND; d += 256) {
    float rn = R_desc[(size_t)n * ND + d];
#pragma unroll
    for (int p = 0; p < NP; ++p) {
      float x = q * (rn - ws->rjp[p][d]);
      xd[p][d] = x;
      acc[p] += x * x;
    }
  }
  __syncthreads();
#pragma unroll
  for (int p = 0; p < NP; ++p) {
    float a = acc[p];
    for (int off = 32; off; off >>= 1) a += __shfl_xor(a, off);
    if ((tid & 63) == 0) atomicAdd(&dist2[p], a);
  }
  __syncthreads();
  if (tid < NP) {
    float dist = sqrtf(dist2[tid]);
    float e = expf(-dist) * qq3;
    e_s[tid] = e;
    e1_s[tid] = e * (1.f + dist);
  }
  __syncthreads();

  // ---- phase 2: inner/v gathers, one thread per (p,a), 3 c's at once ----
  for (int it = tid; it < NP * NA; it += 256) {
    int a = it % NA, p = it / NA;
    float v0 = 0.f, v1 = 0.f, v2 = 0.f;
    float i0 = 0.f, i1 = 0.f, i2 = 0.f;
    const unsigned int* gt = &ws->gtab[a][p][0];
    for (int k = 0; k < NNB; ++k) {
      unsigned int u = gt[k];
      int d  = u & 511;
      int di = (u >> 9) & 511;
      float s = (u & (1u << 27)) ? 1.f : -1.f;
      float xv = s * xd[p][d];
      float xi = s * xd[p][di];
      v0 += xv * Rdn_l[d][0];
      v1 += xv * Rdn_l[d][1];
      v2 += xv * Rdn_l[d][2];
      i0 += xi * Rdj_l[d][0];
      i1 += xi * Rdj_l[d][1];
      i2 += xi * Rdj_l[d][2];
    }
    float e = e_s[p];
    v_s[p][3 * a + 0] = e * v0;
    v_s[p][3 * a + 1] = e * v1;
    v_s[p][3 * a + 2] = e * v2;
    inner_s[p][3 * a + 0] = i0;
    inner_s[p][3 * a + 1] = i1;
    inner_s[p][3 * a + 2] = i2;
  }
  __syncthreads();   // last reader of xd

  // ---- phase 3: single-term part of T, one thread per (a,a2) 3x3 tile ----
  for (int it = tid; it < NA * NA; it += 256) {
    int a2 = it % NA, a = it / NA;
    float m00 = 0.f, m01 = 0.f, m02 = 0.f;
    float m10 = 0.f, m11 = 0.f, m12 = 0.f;
    float m20 = 0.f, m21 = 0.f, m22 = 0.f;
    const unsigned int* st = &ws->stab[a][a2][0];
#pragma unroll
    for (int p = 0; p < NP; ++p) {
      unsigned int u = st[p];
      unsigned code = (u >> 18) & 3u;
      float e1 = e1_s[p];
      float f = (code == 1u) ? e1 : ((code == 2u) ? -e1 : 0.f);
      int d1 = u & 511;
      int d2 = (u >> 9) & 511;
      float r0 = f * Rdn_l[d1][0];
      float r1 = f * Rdn_l[d1][1];
      float r2 = f * Rdn_l[d1][2];
      float j0 = Rdj_l[d2][0];
      float j1 = Rdj_l[d2][1];
      float j2 = Rdj_l[d2][2];
      m00 += r0 * j0; m01 += r0 * j1; m02 += r0 * j2;
      m10 += r1 * j0; m11 += r1 * j1; m12 += r1 * j2;
      m20 += r2 * j0; m21 += r2 * j1; m22 += r2 * j2;
    }
    float* t0 = &buf[(3 * a + 0) * NI + 3 * a2];
    float* t1 = &buf[(3 * a + 1) * NI + 3 * a2];
    float* t2 = &buf[(3 * a + 2) * NI + 3 * a2];
    t0[0] = m00; t0[1] = m01; t0[2] = m02;
    t1[0] = m10; t1[1] = m11; t1[2] = m12;
    t2[0] = m20; t2[1] = m21; t2[2] = m22;
  }
  __syncthreads();

  // ---- phase 4: heavy blocks, one thread per (a,p), atomicAdd into T ----
  for (int it = tid; it < NA * NP; it += 256) {
    int a = it % NA, p = it / NA;
    float h00 = 0.f, h01 = 0.f, h02 = 0.f;
    float h10 = 0.f, h11 = 0.f, h12 = 0.f;
    float h20 = 0.f, h21 = 0.f, h22 = 0.f;
    const unsigned int* gt = &ws->gtab[a][p][0];
    for (int k = 0; k < NNB; ++k) {
      unsigned int u = gt[k];
      int d  = u & 511;
      int d2 = (u >> 18) & 511;
      float sg = (u & (1u << 28)) ? 1.f : -1.f;
      float r0 = sg * Rdn_l[d][0];
      float r1 = sg * Rdn_l[d][1];
      float r2 = sg * Rdn_l[d][2];
      float j0 = Rdj_l[d2][0];
      float j1 = Rdj_l[d2][1];
      float j2 = Rdj_l[d2][2];
      h00 += r0 * j0; h01 += r0 * j1; h02 += r0 * j2;
      h10 += r1 * j0; h11 += r1 * j1; h12 += r1 * j2;
      h20 += r2 * j0; h21 += r2 * j1; h22 += r2 * j2;
    }
    int a2 = ws->sigma[p][a];
    float e1 = e1_s[p];
    atomicAdd(&buf[(3 * a + 0) * NI + 3 * a2 + 0], e1 * h00);
    atomicAdd(&buf[(3 * a + 0) * NI + 3 * a2 + 1], e1 * h01);
    atomicAdd(&buf[(3 * a + 0) * NI + 3 * a2 + 2], e1 * h02);
    atomicAdd(&buf[(3 * a + 1) * NI + 3 * a2 + 0], e1 * h10);
    atomicAdd(&buf[(3 * a + 1) * NI + 3 * a2 + 1], e1 * h11);
    atomicAdd(&buf[(3 * a + 1) * NI + 3 * a2 + 2], e1 * h12);
    atomicAdd(&buf[(3 * a + 2) * NI + 3 * a2 + 0], e1 * h20);
    atomicAdd(&buf[(3 * a + 2) * NI + 3 * a2 + 1], e1 * h21);
    atomicAdd(&buf[(3 * a + 2) * NI + 3 * a2 + 2], e1 * h22);
  }
  __syncthreads();

  // ---- phase 5: final streaming assembly ----
  float* outn = out + (size_t)n * (NI * NI);
  for (int it = tid; it < NI * NI; it += 256) {
    int kk = it / NI, i = it % NI;
    float accv = -buf[it];
#pragma unroll
    for (int p = 0; p < NP; ++p) {
      accv += v_s[p][kk] * inner_s[p][i];
    }
    outn[it] = accv;
  }
}

extern "C" void kernel_launch(void* const* d_in, const int* in_sizes, int n_in,
                              void* d_out, int out_size, void* d_ws, size_t ws_size,
                              hipStream_t stream) {
  const float* R_desc   = (const float*)d_in[0];
  const float* R_d_desc = (const float*)d_in[1];
  const int*   tpl      = (const int*)d_in[2];
  const int*   jptr     = (const int*)d_in[3];
  float* out = (float*)d_out;
  Pre* ws = (Pre*)d_ws;

  const int n_train = in_sizes[0] / ND;

  hipLaunchKernelGGL(pre_kernel, dim3(1), dim3(256), 0, stream,
                     R_desc, R_d_desc, tpl, jptr, ws);
  hipLaunchKernelGGL(gdml_kernel, dim3(n_train), dim3(256), 0, stream,
                     R_desc, R_d_desc, ws, out);
}

// Round 3
// 182.293 us; speedup vs baseline: 4.7621x; 1.2074x over previous
//
#include <hip/hip_runtime.h>
#include <math.h>

#define NA 30
#define ND 435          // NA*(NA-1)/2
#define NI 90           // 3*NA
#define NP 12
#define NNB (NA-1)
#define NT_MAX 2048

struct Pre {
  int   pidx[NP][ND];      // pair permutation: d -> image pair under perm p
  int   pinv[NP][ND];      // inverse pair permutation
  int   sigma[NP][NA];     // atom permutation
  int   sigma_inv[NP][NA];
  int   rowv[ND];
  int   colv[ND];
  int   nbr[NA][NNB];      // the 29 pairs containing atom a
  float rjp[NP][ND];       // R_desc[j][pidx[p][d]]
  float rdj[ND][3];        // R_d_desc[j]
  // gtab: d | pinv<<9 | pidx<<18 | (s(d,a)>0)<<27 | (s(d,a)*s(d2,sigma_p(a))>0)<<28
  unsigned int gtab[NA][NP][NNB];
  // stab: d1 | d2<<9 | code<<18   code: 0=heavy(skip), 1=+, 2=-
  alignas(16) unsigned int stab[NA][NA][NP];
  unsigned int hmask[NA][NA];   // bit p set iff sigma_p(a)==a2
  float eg[NT_MAX * NP];
  float e1g[NT_MAX * NP];
};

__device__ __forceinline__ int pair_index(int x, int y) {
  int hi = max(x, y), lo = min(x, y);
  return hi * (hi - 1) / 2 + lo;
}

__global__ void pre_kernel(const float* __restrict__ R_desc,
                           const float* __restrict__ R_d_desc,
                           const int* __restrict__ tpl,
                           const int* __restrict__ jptr,
                           Pre* ws) {
  const int tid = threadIdx.x;
  const int nthr = blockDim.x;
  const int j = *jptr;

  for (int idx = tid; idx < NA * NA; idx += nthr)
    ws->hmask[idx / NA][idx % NA] = 0u;
  for (int d = tid; d < ND; d += nthr) {
    int a = (int)floorf((1.0f + sqrtf(1.0f + 8.0f * (float)d)) * 0.5f);
    while (a * (a - 1) / 2 > d) --a;
    while ((a + 1) * a / 2 <= d) ++a;
    ws->rowv[d] = a;
    ws->colv[d] = d - a * (a - 1) / 2;
  }
  for (int idx = tid; idx < NP * ND; idx += nthr) {
    int d = idx / NP, p = idx % NP;          // tpl layout: [d*NP + p]
    int t = tpl[idx] - p * ND;
    ws->pidx[p][d] = t;
    ws->rjp[p][d] = R_desc[(size_t)j * ND + t];
  }
  for (int idx = tid; idx < ND * 3; idx += nthr) {
    ((float*)ws->rdj)[idx] = R_d_desc[(size_t)j * (ND * 3) + idx];
  }
  for (int a = tid; a < NA; a += nthr) {
    int k = 0;
    for (int u = 0; u < NA; ++u)
      if (u != a) ws->nbr[a][k++] = pair_index(a, u);
  }
  __syncthreads();
  for (int idx = tid; idx < NP * ND; idx += nthr) {
    int d = idx / NP, p = idx % NP;
    ws->pinv[p][ws->pidx[p][d]] = d;
  }
  // recover atom permutation sigma_p
  for (int idx = tid; idx < NP * NA; idx += nthr) {
    int p = idx / NA, a = idx % NA;
    int u1 = (a == 0) ? 1 : 0;
    int u2 = (a <= 1) ? 2 : 1;
    int e1 = ws->pidx[p][pair_index(a, u1)];
    int e2 = ws->pidx[p][pair_index(a, u2)];
    int r1 = ws->rowv[e1], c1 = ws->colv[e1];
    int r2 = ws->rowv[e2], c2 = ws->colv[e2];
    int sa = (r1 == r2 || r1 == c2) ? r1 : c1;
    ws->sigma[p][a] = sa;
  }
  __syncthreads();
  for (int idx = tid; idx < NP * NA; idx += nthr) {
    int p = idx / NA, a = idx % NA;
    ws->sigma_inv[p][ws->sigma[p][a]] = a;
  }
  __syncthreads();
  // gtab + hmask
  for (int idx = tid; idx < NA * NP * NNB; idx += nthr) {
    int k = idx % NNB;
    int r = idx / NNB;
    int p = r % NP, a = r / NP;
    int d  = ws->nbr[a][k];
    int di = ws->pinv[p][d];
    int d2 = ws->pidx[p][d];
    int s1 = (ws->rowv[d] == a) ? 1 : 0;
    int a2h = ws->sigma[p][a];
    int s2 = (ws->rowv[d2] == a2h) ? 1 : 0;
    unsigned int u = (unsigned)d | ((unsigned)di << 9) | ((unsigned)d2 << 18);
    if (s1) u |= (1u << 27);
    if (s1 == s2) u |= (1u << 28);
    ws->gtab[a][p][k] = u;
  }
  for (int idx = tid; idx < NP * NA; idx += nthr) {
    int p = idx / NA, a = idx % NA;
    atomicOr(&ws->hmask[a][ws->sigma[p][a]], 1u << p);
  }
  // stab
  for (int idx = tid; idx < NA * NA * NP; idx += nthr) {
    int p = idx % NP;
    int r = idx / NP;
    int a2 = r % NA, a = r / NA;
    unsigned int u;
    if (ws->sigma[p][a] == a2) {
      u = 0;  // heavy column: handled via hmask/Hh
    } else {
      int uu = ws->sigma_inv[p][a2];
      int d1 = pair_index(a, uu);
      int d2 = ws->pidx[p][d1];
      int s1 = (ws->rowv[d1] == a) ? 1 : 0;
      int s2 = (ws->rowv[d2] == a2) ? 1 : 0;
      unsigned code = (s1 == s2) ? 1u : 2u;
      u = (unsigned)d1 | ((unsigned)d2 << 9) | (code << 18);
    }
    ws->stab[a][a2][p] = u;
  }
}

// e/e1 per (n,p): one wave per n
__global__ __launch_bounds__(64) void dist_kernel(const float* __restrict__ R_desc,
                                                  Pre* __restrict__ ws) {
  const int n = blockIdx.x;
  const int lane = threadIdx.x;
  const float q   = 0.22360679774997896f;   // sqrt(5)/10
  const float qq3 = 0.016666666666666666f;  // q*q/3
  float rn[7];
#pragma unroll
  for (int i = 0; i < 7; ++i) {
    int d = lane + 64 * i;
    rn[i] = (d < ND) ? R_desc[(size_t)n * ND + d] : 0.f;
  }
#pragma unroll
  for (int p = 0; p < NP; ++p) {
    float acc = 0.f;
#pragma unroll
    for (int i = 0; i < 7; ++i) {
      int d = lane + 64 * i;
      if (d < ND) {
        float x = q * (rn[i] - ws->rjp[p][d]);
        acc += x * x;
      }
    }
    for (int off = 32; off; off >>= 1) acc += __shfl_xor(acc, off);
    if (lane == 0) {
      float dist = sqrtf(acc);
      float e = expf(-dist) * qq3;
      ws->eg[n * NP + p] = e;
      ws->e1g[n * NP + p] = e * (1.f + dist);
    }
  }
}

__global__ __launch_bounds__(256) void gdml_kernel(
    const float* __restrict__ R_desc,
    const float* __restrict__ R_d_desc,
    const Pre* __restrict__ ws,
    float* __restrict__ out) {
  const int n = blockIdx.x;
  const int tid = threadIdx.x;

  __shared__ float U[NP * ND];       // 20.9 KB: xd, then Hh overlay
  __shared__ float Rdn_l[ND][3];     // 5.2 KB
  __shared__ float Rdj_l[ND][3];     // 5.2 KB
  __shared__ float v_s[NP][NI];      // 4.3 KB  (pre-scaled by e_p)
  __shared__ float inner_s[NP][NI];  // 4.3 KB
  // total 39.96 KB -> 4 blocks/CU

  float (*xd)[ND] = (float(*)[ND])U;
  float (*Hh)[NP * 9] = (float(*)[NP * 9])U;   // [NA][NP*9] = 3240 floats

  const float q = 0.22360679774997896f;   // sqrt(5)/10
  const float* e1p = ws->e1g + (size_t)n * NP;
  const float* ep  = ws->eg  + (size_t)n * NP;

  // ---- P1: load Rdn/Rdj, compute xd (no reduction) ----
  for (int idx = tid; idx < ND * 3; idx += 256) {
    ((float*)Rdn_l)[idx] = R_d_desc[(size_t)n * (ND * 3) + idx];
    ((float*)Rdj_l)[idx] = ((const float*)ws->rdj)[idx];
  }
  for (int d = tid; d < ND; d += 256) {
    float rn = R_desc[(size_t)n * ND + d];
#pragma unroll
    for (int p = 0; p < NP; ++p) xd[p][d] = q * (rn - ws->rjp[p][d]);
  }
  __syncthreads();

  // ---- P2: inner/v gathers, one thread per (p,a) ----
  for (int it = tid; it < NP * NA; it += 256) {
    int a = it % NA, p = it / NA;
    float v0 = 0.f, v1 = 0.f, v2 = 0.f;
    float i0 = 0.f, i1 = 0.f, i2 = 0.f;
    const unsigned int* gt = &ws->gtab[a][p][0];
    for (int k = 0; k < NNB; ++k) {
      unsigned int u = gt[k];
      int d  = u & 511;
      int di = (u >> 9) & 511;
      float s = (u & (1u << 27)) ? 1.f : -1.f;
      float xv = s * xd[p][d];
      float xi = s * xd[p][di];
      v0 += xv * Rdn_l[d][0];
      v1 += xv * Rdn_l[d][1];
      v2 += xv * Rdn_l[d][2];
      i0 += xi * Rdj_l[d][0];
      i1 += xi * Rdj_l[d][1];
      i2 += xi * Rdj_l[d][2];
    }
    float e = ep[p];
    v_s[p][3 * a + 0] = e * v0;
    v_s[p][3 * a + 1] = e * v1;
    v_s[p][3 * a + 2] = e * v2;
    inner_s[p][3 * a + 0] = i0;
    inner_s[p][3 * a + 1] = i1;
    inner_s[p][3 * a + 2] = i2;
  }
  __syncthreads();   // xd dead beyond here; U becomes Hh

  // ---- P4: heavy blocks into Hh (unscaled), plain stores ----
  for (int it = tid; it < NA * NP; it += 256) {
    int a = it % NA, p = it / NA;
    float h00 = 0.f, h01 = 0.f, h02 = 0.f;
    float h10 = 0.f, h11 = 0.f, h12 = 0.f;
    float h20 = 0.f, h21 = 0.f, h22 = 0.f;
    const unsigned int* gt = &ws->gtab[a][p][0];
    for (int k = 0; k < NNB; ++k) {
      unsigned int u = gt[k];
      int d  = u & 511;
      int d2 = (u >> 18) & 511;
      float sg = (u & (1u << 28)) ? 1.f : -1.f;
      float r0 = sg * Rdn_l[d][0];
      float r1 = sg * Rdn_l[d][1];
      float r2 = sg * Rdn_l[d][2];
      float j0 = Rdj_l[d2][0];
      float j1 = Rdj_l[d2][1];
      float j2 = Rdj_l[d2][2];
      h00 += r0 * j0; h01 += r0 * j1; h02 += r0 * j2;
      h10 += r1 * j0; h11 += r1 * j1; h12 += r1 * j2;
      h20 += r2 * j0; h21 += r2 * j1; h22 += r2 * j2;
    }
    float* hb = &Hh[a][p * 9];
    hb[0] = h00; hb[1] = h01; hb[2] = h02;
    hb[3] = h10; hb[4] = h11; hb[5] = h12;
    hb[6] = h20; hb[7] = h21; hb[8] = h22;
  }
  __syncthreads();

  // ---- P5: fused output, one thread per (a,a2) 3x3 block ----
  float* outn = out + (size_t)n * (NI * NI);
  for (int it = tid; it < NA * NA; it += 256) {
    int a = it / NA, a2 = it % NA;
    float acc0 = 0.f, acc1 = 0.f, acc2 = 0.f;
    float acc3 = 0.f, acc4 = 0.f, acc5 = 0.f;
    float acc6 = 0.f, acc7 = 0.f, acc8 = 0.f;
    const uint4* st4 = (const uint4*)&ws->stab[a][a2][0];
    uint4 ua = st4[0], ub = st4[1], uc = st4[2];
    unsigned stv[12] = {ua.x, ua.y, ua.z, ua.w, ub.x, ub.y, ub.z, ub.w,
                        uc.x, uc.y, uc.z, uc.w};
#pragma unroll
    for (int p = 0; p < NP; ++p) {
      // rank-12 part
      float v0 = v_s[p][3 * a + 0];
      float v1 = v_s[p][3 * a + 1];
      float v2 = v_s[p][3 * a + 2];
      float w0 = inner_s[p][3 * a2 + 0];
      float w1 = inner_s[p][3 * a2 + 1];
      float w2 = inner_s[p][3 * a2 + 2];
      acc0 += v0 * w0; acc1 += v0 * w1; acc2 += v0 * w2;
      acc3 += v1 * w0; acc4 += v1 * w1; acc5 += v1 * w2;
      acc6 += v2 * w0; acc7 += v2 * w1; acc8 += v2 * w2;
      // single-term part (f=0 on heavy columns)
      unsigned u = stv[p];
      unsigned code = (u >> 18) & 3u;
      float e1 = e1p[p];
      float f = (code == 1u) ? e1 : ((code == 2u) ? -e1 : 0.f);
      int d1 = u & 511;
      int d2 = (u >> 9) & 511;
      float r0 = f * Rdn_l[d1][0];
      float r1 = f * Rdn_l[d1][1];
      float r2 = f * Rdn_l[d1][2];
      float j0 = Rdj_l[d2][0];
      float j1 = Rdj_l[d2][1];
      float j2 = Rdj_l[d2][2];
      acc0 -= r0 * j0; acc1 -= r0 * j1; acc2 -= r0 * j2;
      acc3 -= r1 * j0; acc4 -= r1 * j1; acc5 -= r1 * j2;
      acc6 -= r2 * j0; acc7 -= r2 * j1; acc8 -= r2 * j2;
    }
    // heavy contributions via bitmask
    unsigned m = ws->hmask[a][a2];
    while (m) {
      int p = __ffs(m) - 1;
      m &= m - 1;
      float e1 = e1p[p];
      const float* hb = &Hh[a][p * 9];
      acc0 -= e1 * hb[0]; acc1 -= e1 * hb[1]; acc2 -= e1 * hb[2];
      acc3 -= e1 * hb[3]; acc4 -= e1 * hb[4]; acc5 -= e1 * hb[5];
      acc6 -= e1 * hb[6]; acc7 -= e1 * hb[7]; acc8 -= e1 * hb[8];
    }
    float* ob = outn + (size_t)(3 * a) * NI + 3 * a2;
    ob[0] = acc0;          ob[1] = acc1;          ob[2] = acc2;
    ob[NI + 0] = acc3;     ob[NI + 1] = acc4;     ob[NI + 2] = acc5;
    ob[2 * NI + 0] = acc6; ob[2 * NI + 1] = acc7; ob[2 * NI + 2] = acc8;
  }
}

extern "C" void kernel_launch(void* const* d_in, const int* in_sizes, int n_in,
                              void* d_out, int out_size, void* d_ws, size_t ws_size,
                              hipStream_t stream) {
  const float* R_desc   = (const float*)d_in[0];
  const float* R_d_desc = (const float*)d_in[1];
  const int*   tpl      = (const int*)d_in[2];
  const int*   jptr     = (const int*)d_in[3];
  float* out = (float*)d_out;
  Pre* ws = (Pre*)d_ws;

  const int n_train = in_sizes[0] / ND;

  hipLaunchKernelGGL(pre_kernel, dim3(1), dim3(256), 0, stream,
                     R_desc, R_d_desc, tpl, jptr, ws);
  hipLaunchKernelGGL(dist_kernel, dim3(n_train), dim3(64), 0, stream,
                     R_desc, ws);
  hipLaunchKernelGGL(gdml_kernel, dim3(n_train), dim3(256), 0, stream,
                     R_desc, R_d_desc, ws, out);
}

// Round 4
// 110.010 us; speedup vs baseline: 7.8911x; 1.6571x over previous
//
#include <hip/hip_runtime.h>
#include <math.h>

#define NA 30
#define ND 435          // NA*(NA-1)/2
#define NI 90           // 3*NA
#define NP 12
#define NNB (NA-1)

typedef float v2f __attribute__((ext_vector_type(2)));

struct Pre {
  int   pidx[NP][ND];      // pair permutation: d -> image pair under perm p
  int   pinv[NP][ND];      // inverse pair permutation
  int   sigma[NP][NA];     // atom permutation
  int   sigma_inv[NP][NA];
  int   rowv[ND];
  int   colv[ND];
  int   nbr[NA][NNB];      // the 29 pairs containing atom a
  float rjp[NP][ND];       // R_desc[j][pidx[p][d]]
  float rdj[ND][3];        // R_d_desc[j]
  // gtab[k][p][a]: d | pinv<<9 | pidx<<18 | s1<<27 | (s1==s2h)<<28  (coalesced in a)
  unsigned int gtab[NNB][NP][NA];
  // stab[a][a2][p]: d1 | d2<<9 | code<<18   code: 0=heavy(skip), 1=+, 2=-
  alignas(16) unsigned int stab[NA][NA][NP];
  unsigned int hmask[NA][NA];   // bit p set iff sigma_p(a)==a2
};

__device__ __forceinline__ int pair_index(int x, int y) {
  int hi = max(x, y), lo = min(x, y);
  return hi * (hi - 1) / 2 + lo;
}

// ---- preA: small dependent graph work, single block ----
__global__ void preA_kernel(const int* __restrict__ tpl, Pre* ws) {
  const int tid = threadIdx.x;
  const int nthr = blockDim.x;

  for (int d = tid; d < ND; d += nthr) {
    int a = (int)floorf((1.0f + sqrtf(1.0f + 8.0f * (float)d)) * 0.5f);
    while (a * (a - 1) / 2 > d) --a;
    while ((a + 1) * a / 2 <= d) ++a;
    ws->rowv[d] = a;
    ws->colv[d] = d - a * (a - 1) / 2;
  }
  for (int a = tid; a < NA; a += nthr) {
    int k = 0;
    for (int u = 0; u < NA; ++u)
      if (u != a) ws->nbr[a][k++] = pair_index(a, u);
  }
  for (int idx = tid; idx < NP * ND; idx += nthr) {
    int d = idx / NP, p = idx % NP;          // tpl layout: [d*NP + p]
    ws->pidx[p][d] = tpl[idx] - p * ND;
  }
  __syncthreads();
  for (int idx = tid; idx < NP * ND; idx += nthr) {
    int d = idx / NP, p = idx % NP;
    ws->pinv[p][ws->pidx[p][d]] = d;
  }
  // recover atom permutation sigma_p
  for (int idx = tid; idx < NP * NA; idx += nthr) {
    int p = idx / NA, a = idx % NA;
    int u1 = (a == 0) ? 1 : 0;
    int u2 = (a <= 1) ? 2 : 1;
    int e1 = ws->pidx[p][pair_index(a, u1)];
    int e2 = ws->pidx[p][pair_index(a, u2)];
    int r1 = ws->rowv[e1], c1 = ws->colv[e1];
    int r2 = ws->rowv[e2], c2 = ws->colv[e2];
    int sa = (r1 == r2 || r1 == c2) ? r1 : c1;
    ws->sigma[p][a] = sa;
  }
  __syncthreads();
  for (int idx = tid; idx < NP * NA; idx += nthr) {
    int p = idx / NA, a = idx % NA;
    ws->sigma_inv[p][ws->sigma[p][a]] = a;
  }
  __syncthreads();
  for (int it = tid; it < NA * NA; it += nthr) {
    int a = it / NA, a2 = it % NA;
    unsigned m = 0;
#pragma unroll
    for (int p = 0; p < NP; ++p)
      if (ws->sigma[p][a] == a2) m |= (1u << p);
    ws->hmask[a][a2] = m;
  }
}

// ---- preB: bulk table fills, grid-parallel ----
__global__ void preB_kernel(const float* __restrict__ R_desc,
                            const float* __restrict__ R_d_desc,
                            const int* __restrict__ jptr,
                            Pre* ws) {
  const int gid = blockIdx.x * blockDim.x + threadIdx.x;
  const int gsz = gridDim.x * blockDim.x;
  const int j = *jptr;

  for (int idx = gid; idx < NP * ND; idx += gsz) {
    int p = idx / ND, d = idx % ND;
    ws->rjp[p][d] = R_desc[(size_t)j * ND + ws->pidx[p][d]];
  }
  for (int idx = gid; idx < ND * 3; idx += gsz)
    ((float*)ws->rdj)[idx] = R_d_desc[(size_t)j * (ND * 3) + idx];

  for (int idx = gid; idx < NNB * NP * NA; idx += gsz) {
    int a = idx % NA;
    int r = idx / NA;
    int p = r % NP, k = r / NP;
    int d  = ws->nbr[a][k];
    int di = ws->pinv[p][d];
    int d2 = ws->pidx[p][d];
    int s1 = (ws->rowv[d] == a) ? 1 : 0;
    int s2 = (ws->rowv[d2] == ws->sigma[p][a]) ? 1 : 0;
    unsigned int u = (unsigned)d | ((unsigned)di << 9) | ((unsigned)d2 << 18);
    if (s1) u |= (1u << 27);
    if (s1 == s2) u |= (1u << 28);
    ws->gtab[k][p][a] = u;
  }
  for (int idx = gid; idx < NA * NA * NP; idx += gsz) {
    int p = idx % NP;
    int r = idx / NP;
    int a2 = r % NA, a = r / NA;
    unsigned int u = 0;
    if (ws->sigma[p][a] != a2) {
      int uu = ws->sigma_inv[p][a2];
      int d1 = pair_index(a, uu);
      int d2 = ws->pidx[p][d1];
      int s1 = (ws->rowv[d1] == a) ? 1 : 0;
      int s2 = (ws->rowv[d2] == a2) ? 1 : 0;
      unsigned code = (s1 == s2) ? 1u : 2u;
      u = (unsigned)d1 | ((unsigned)d2 << 9) | (code << 18);
    }
    ws->stab[a][a2][p] = u;
  }
}

__global__ __launch_bounds__(256) void gdml_kernel(
    const float* __restrict__ R_desc,
    const float* __restrict__ R_d_desc,
    const Pre* __restrict__ ws,
    float* __restrict__ out) {
  const int n = blockIdx.x;
  const int tid = threadIdx.x;

  __shared__ float U[NP * ND];       // 20.9 KB: xd, then Hh overlay
  __shared__ float Rdn_l[ND][3];     // 5.2 KB
  __shared__ float Rdj_l[ND][3];     // 5.2 KB
  __shared__ float v_s[NP][NI];      // 4.3 KB  (pre-scaled by e_p)
  __shared__ float inner_s[NP][NI];  // 4.3 KB
  __shared__ float e_s[NP], e1_s[NP];
  // total ~40.1 KB -> 4 blocks/CU

  float* xd = U;                                 // [NP][ND]
  float (*Hh)[NP * 9] = (float(*)[NP * 9])U;     // overlay after xd is dead

  const float q   = 0.22360679774997896f;   // sqrt(5)/10
  const float qq3 = 0.016666666666666666f;  // q*q/3

  // ---- P1: load Rdn/Rdj, compute xd ----
  for (int idx = tid; idx < ND * 3; idx += 256) {
    ((float*)Rdn_l)[idx] = R_d_desc[(size_t)n * (ND * 3) + idx];
    ((float*)Rdj_l)[idx] = ((const float*)ws->rdj)[idx];
  }
  for (int d = tid; d < ND; d += 256) {
    float rn = R_desc[(size_t)n * ND + d];
#pragma unroll
    for (int p = 0; p < NP; ++p) xd[p * ND + d] = q * (rn - ws->rjp[p][d]);
  }
  __syncthreads();

  // ---- dist: wave w handles perms 3w..3w+2, reading xd from LDS ----
  {
    int w = tid >> 6, lane = tid & 63;
#pragma unroll
    for (int pp = 0; pp < 3; ++pp) {
      int p = 3 * w + pp;
      float acc = 0.f;
#pragma unroll
      for (int i = 0; i < 7; ++i) {
        int d = lane + 64 * i;
        if (d < ND) { float x = xd[p * ND + d]; acc += x * x; }
      }
      for (int off = 32; off; off >>= 1) acc += __shfl_xor(acc, off);
      if (lane == 0) {
        float dist = sqrtf(acc);
        float e = expf(-dist) * qq3;
        e_s[p] = e;
        e1_s[p] = e * (1.f + dist);
      }
    }
  }
  __syncthreads();

  // ---- P2': fused v/inner/H per (p,a); H kept in registers ----
  auto p2_item = [&](int it, float (&h)[9]) {
    int a = it % NA, p = it / NA;
    const float* xdp = xd + p * ND;
    float v0 = 0.f, v1 = 0.f, v2 = 0.f;
    float i0 = 0.f, i1 = 0.f, i2 = 0.f;
    v2f H0 = {0.f, 0.f}, H1 = {0.f, 0.f}, H2 = {0.f, 0.f};
    float Hc0 = 0.f, Hc1 = 0.f, Hc2 = 0.f;
    for (int k = 0; k < NNB; ++k) {
      unsigned int u = ws->gtab[k][p][a];
      int d  = u & 511;
      int di = (u >> 9) & 511;
      int d2 = (u >> 18) & 511;
      float s  = (u & (1u << 27)) ? 1.f : -1.f;
      float sg = (u & (1u << 28)) ? 1.f : -1.f;
      float xv = s * xdp[d];
      float xi = s * xdp[di];
      float n0 = Rdn_l[d][0], n1 = Rdn_l[d][1], n2 = Rdn_l[d][2];
      float jd0 = Rdj_l[d][0], jd1 = Rdj_l[d][1], jd2 = Rdj_l[d][2];
      float jb0 = Rdj_l[d2][0], jb1 = Rdj_l[d2][1], jb2 = Rdj_l[d2][2];
      v0 += xv * n0; v1 += xv * n1; v2 += xv * n2;
      i0 += xi * jd0; i1 += xi * jd1; i2 += xi * jd2;
      float r0 = sg * n0, r1 = sg * n1, r2 = sg * n2;
      v2f jb01 = {jb0, jb1};
      H0 += (v2f){r0, r0} * jb01; Hc0 += r0 * jb2;
      H1 += (v2f){r1, r1} * jb01; Hc1 += r1 * jb2;
      H2 += (v2f){r2, r2} * jb01; Hc2 += r2 * jb2;
    }
    float e = e_s[p];
    v_s[p][3 * a + 0] = e * v0;
    v_s[p][3 * a + 1] = e * v1;
    v_s[p][3 * a + 2] = e * v2;
    inner_s[p][3 * a + 0] = i0;
    inner_s[p][3 * a + 1] = i1;
    inner_s[p][3 * a + 2] = i2;
    h[0] = H0.x; h[1] = H0.y; h[2] = Hc0;
    h[3] = H1.x; h[4] = H1.y; h[5] = Hc1;
    h[6] = H2.x; h[7] = H2.y; h[8] = Hc2;
  };

  float h1[9], h2[9];
  const int it1 = tid;
  const int it2 = tid + 256;
  const bool has2 = (it2 < NP * NA);
  p2_item(it1, h1);
  if (has2) p2_item(it2, h2);
  __syncthreads();   // all xd reads done; U becomes Hh

  {
    int a = it1 % NA, p = it1 / NA;
    float* hb = &Hh[a][p * 9];
#pragma unroll
    for (int r = 0; r < 9; ++r) hb[r] = h1[r];
  }
  if (has2) {
    int a = it2 % NA, p = it2 / NA;
    float* hb = &Hh[a][p * 9];
#pragma unroll
    for (int r = 0; r < 9; ++r) hb[r] = h2[r];
  }
  __syncthreads();

  // ---- P5: fused output, one thread per (a,a2) 3x3 block ----
  float e1r[NP];
#pragma unroll
  for (int p = 0; p < NP; ++p) e1r[p] = e1_s[p];

  float* outn = out + (size_t)n * (NI * NI);
  for (int it = tid; it < NA * NA; it += 256) {
    int a = it / NA, a2 = it % NA;
    v2f A0 = {0.f, 0.f}, A1 = {0.f, 0.f}, A2 = {0.f, 0.f};
    float B0 = 0.f, B1 = 0.f, B2 = 0.f;
    const uint4* st4 = (const uint4*)&ws->stab[a][a2][0];
    uint4 ua = st4[0], ub = st4[1], uc = st4[2];
    unsigned stv[12] = {ua.x, ua.y, ua.z, ua.w, ub.x, ub.y, ub.z, ub.w,
                        uc.x, uc.y, uc.z, uc.w};
#pragma unroll
    for (int p = 0; p < NP; ++p) {
      float v0 = v_s[p][3 * a + 0];
      float v1 = v_s[p][3 * a + 1];
      float v2v = v_s[p][3 * a + 2];
      float w0 = inner_s[p][3 * a2 + 0];
      float w1 = inner_s[p][3 * a2 + 1];
      float w2 = inner_s[p][3 * a2 + 2];
      v2f w01 = {w0, w1};
      A0 += (v2f){v0, v0} * w01;   B0 += v0 * w2;
      A1 += (v2f){v1, v1} * w01;   B1 += v1 * w2;
      A2 += (v2f){v2v, v2v} * w01; B2 += v2v * w2;
      unsigned u = stv[p];
      unsigned code = (u >> 18) & 3u;
      float e1 = e1r[p];
      float f = (code == 1u) ? -e1 : ((code == 2u) ? e1 : 0.f);  // minus folded in
      int d1 = u & 511;
      int d2 = (u >> 9) & 511;
      float r0 = f * Rdn_l[d1][0];
      float r1 = f * Rdn_l[d1][1];
      float r2 = f * Rdn_l[d1][2];
      float j0 = Rdj_l[d2][0], j1 = Rdj_l[d2][1], j2 = Rdj_l[d2][2];
      v2f j01 = {j0, j1};
      A0 += (v2f){r0, r0} * j01;   B0 += r0 * j2;
      A1 += (v2f){r1, r1} * j01;   B1 += r1 * j2;
      A2 += (v2f){r2, r2} * j01;   B2 += r2 * j2;
    }
    unsigned m = ws->hmask[a][a2];
    while (m) {
      int p = __ffs(m) - 1;
      m &= m - 1;
      float e1 = e1r[p];
      const float* hb = &Hh[a][p * 9];
      A0 -= e1 * (v2f){hb[0], hb[1]}; B0 -= e1 * hb[2];
      A1 -= e1 * (v2f){hb[3], hb[4]}; B1 -= e1 * hb[5];
      A2 -= e1 * (v2f){hb[6], hb[7]}; B2 -= e1 * hb[8];
    }
    float* ob = outn + (size_t)(3 * a) * NI + 3 * a2;
    ob[0] = A0.x;          ob[1] = A0.y;          ob[2] = B0;
    ob[NI + 0] = A1.x;     ob[NI + 1] = A1.y;     ob[NI + 2] = B1;
    ob[2 * NI + 0] = A2.x; ob[2 * NI + 1] = A2.y; ob[2 * NI + 2] = B2;
  }
}

extern "C" void kernel_launch(void* const* d_in, const int* in_sizes, int n_in,
                              void* d_out, int out_size, void* d_ws, size_t ws_size,
                              hipStream_t stream) {
  const float* R_desc   = (const float*)d_in[0];
  const float* R_d_desc = (const float*)d_in[1];
  const int*   tpl      = (const int*)d_in[2];
  const int*   jptr     = (const int*)d_in[3];
  float* out = (float*)d_out;
  Pre* ws = (Pre*)d_ws;

  const int n_train = in_sizes[0] / ND;

  hipLaunchKernelGGL(preA_kernel, dim3(1), dim3(256), 0, stream, tpl, ws);
  hipLaunchKernelGGL(preB_kernel, dim3(48), dim3(256), 0, stream,
                     R_desc, R_d_desc, jptr, ws);
  hipLaunchKernelGGL(gdml_kernel, dim3(n_train), dim3(256), 0, stream,
                     R_desc, R_d_desc, ws, out);
}